// Round 8
// baseline (114.066 us; speedup 1.0000x reference)
//
#include <hip/hip_runtime.h>
#include <hip/hip_bf16.h>
#include <cstdint>

// MultiRelationalGraphDiffusion: out = LeakyReLU( sum_k conv_w[k] * (adj_norm^k @ (h@W^T)) + conv_b )
// B=8, N=2048, D=256, K=4.
//
// Round-8 (on R7's counted-vmcnt pipeline):
//  - XCD pair-swizzle: o-half blocks sharing adjq/h rows are 8 block-IDs apart -> same
//    XCD under round-robin dispatch -> 2nd read is L2-hit (halves d-step L3 traffic).
//  - diffuse: stage-ahead-3, NBUF=6 (72 KB, 2 blk/CU): ~700cyc cover vs L3 ~600-900cyc.
//    Ledger: write buf (t+3)%6 at iter t; last read at compute(t-3); any wave past
//    barrier(t-1) finished compute(t-2) >= t-3. vmcnt(9) = 3 tiles x 3 loads in flight.
//  - t intermediate stored fp16 (8.4 MB) instead of out f32 (16.8): d3 reads t, writes
//    out exactly once (no RMW). fp16 err <= 0.001*|t|*|cw0| ~ 0.005, inside budget.
// Scales: adjS=256*adj_norm, cS=16*c -> acc=4096*(adj@c); next cS=acc/256; last tap acc/4096.

#define BATCH 8
#define NN    2048
#define DD    256
#define REPS  1e-9f
#define SLOPE 0.2f

typedef __bf16 bf16x8_t __attribute__((ext_vector_type(8)));
typedef __bf16 bf16x4_t __attribute__((ext_vector_type(4)));
typedef float  f32x4_t  __attribute__((ext_vector_type(4)));

__device__ __forceinline__ void gl2lds16(const void* g, void* l) {
    __builtin_amdgcn_global_load_lds(
        (const __attribute__((address_space(1))) unsigned int*)(uintptr_t)g,
        (__attribute__((address_space(3))) unsigned int*)(unsigned int)(uintptr_t)l,
        16, 0, 0);
}

__device__ __forceinline__ unsigned int pk_fp8x4(float a, float b, float c, float d) {
    int lo = __builtin_amdgcn_cvt_pk_fp8_f32(a, b, 0, false);
    return (unsigned int)__builtin_amdgcn_cvt_pk_fp8_f32(c, d, lo, true);
}

__device__ __forceinline__ f32x4_t cvt_f32_fp8x4(unsigned int u) {
    f32x4_t r;
    r[0] = __builtin_amdgcn_cvt_f32_fp8(u, 0);
    r[1] = __builtin_amdgcn_cvt_f32_fp8(u, 1);
    r[2] = __builtin_amdgcn_cvt_f32_fp8(u, 2);
    r[3] = __builtin_amdgcn_cvt_f32_fp8(u, 3);
    return r;
}

// swizzled byte position of logical byte n within a row keyed by `key`
__device__ __forceinline__ int swz(int n, int key) {
    return (n & ~63) | ((((n >> 3) & 7) ^ key) << 3) | (n & 7);
}

// pair-XCD remap: linear p -> (n0, o0, b) with the two o-halves of one (n0,b)
// exactly 8 apart (round-robin XCD: p%8 == (p+8)%8 -> same XCD, shared rows L2-hit)
__device__ __forceinline__ void pair_remap(int& n0, int& o0, int& b) {
    const int p = blockIdx.x + 32 * (blockIdx.y + 2 * blockIdx.z);
    const int g = p >> 4, r = p & 15;
    o0 = (r >> 3) * 128;
    const int nb = g * 8 + (r & 7);
    n0 = (nb & 31) * 64;
    b  = nb >> 5;
}

// ================= normadj: wave-per-row, no LDS, fp8 x256, uint2 stores =================
__global__ __launch_bounds__(256) void k_normadj(const float* __restrict__ adj,
                                                 unsigned char* __restrict__ adjq) {
    const int l = threadIdx.x & 63;
    const int row = blockIdx.x * 4 + (threadIdx.x >> 6);   // b*NN + n
    const float* src = adj + (size_t)row * NN;
    f32x4_t v[8];
#pragma unroll
    for (int q = 0; q < 4; ++q) {
        v[2 * q]     = *(const f32x4_t*)(src + q * 512 + l * 8);
        v[2 * q + 1] = *(const f32x4_t*)(src + q * 512 + l * 8 + 4);
    }
    float s = 0.f;
#pragma unroll
    for (int j = 0; j < 8; ++j) s += v[j][0] + v[j][1] + v[j][2] + v[j][3];
#pragma unroll
    for (int m = 1; m < 64; m <<= 1) s += __shfl_xor(s, m, 64);
    const float sc = 256.0f / (s + REPS);
    const int key = row & 7;
    unsigned char* drow = adjq + (size_t)row * NN;
#pragma unroll
    for (int q = 0; q < 4; ++q) {
        uint2 u;
        u.x = pk_fp8x4(v[2 * q][0] * sc, v[2 * q][1] * sc, v[2 * q][2] * sc, v[2 * q][3] * sc);
        u.y = pk_fp8x4(v[2 * q + 1][0] * sc, v[2 * q + 1][1] * sc,
                       v[2 * q + 1][2] * sc, v[2 * q + 1][3] * sc);
        *(uint2*)(drow + swz(q * 512 + l * 8, key)) = u;
    }
}

// ================= htrans: bf16x3 MFMA; t_h fp16, c0q = fp8(16t) =================
__global__ __launch_bounds__(256) void k_htrans(const float* __restrict__ h,
                                                const float* __restrict__ W,
                                                _Float16* __restrict__ t_h,
                                                unsigned char* __restrict__ c0q) {
    __shared__ __align__(16) __bf16 Ah[64 * 64], Al[64 * 64];
    __shared__ __align__(16) __bf16 Bh[128 * 64], Bl[128 * 64];

    const int tid = threadIdx.x;
    int n0, o0, b;
    pair_remap(n0, o0, b);
    const int lane = tid & 63, wv = tid >> 6;
    const int wr = wv >> 1, wc = wv & 1;
    const int rl = lane & 15, kq = lane >> 4;
    const int ar = tid >> 4, ac = (tid & 15) * 4;

    f32x4_t acc[2][4];
#pragma unroll
    for (int i = 0; i < 2; ++i)
#pragma unroll
        for (int j = 0; j < 4; ++j) acc[i][j] = (f32x4_t){0.f, 0.f, 0.f, 0.f};

    for (int kt = 0; kt < 4; ++kt) {
        const int k0 = kt * 64;
#pragma unroll
        for (int q = 0; q < 4; ++q) {
            const int r = q * 16 + ar;
            f32x4_t v = *(const f32x4_t*)(h + ((size_t)b * NN + n0 + r) * DD + k0 + ac);
            bf16x4_t hi4, lo4;
#pragma unroll
            for (int e = 0; e < 4; ++e) {
                float x = v[e];
                __bf16 hh = (__bf16)x;
                hi4[e] = hh;
                lo4[e] = (__bf16)(x - (float)hh);
            }
            const int off = r * 128 + (((ac >> 3) ^ (r & 7)) << 4) + (ac & 7) * 2;
            *(bf16x4_t*)((char*)Ah + off) = hi4;
            *(bf16x4_t*)((char*)Al + off) = lo4;
        }
#pragma unroll
        for (int q = 0; q < 8; ++q) {
            const int r = q * 16 + ar;
            f32x4_t v = *(const f32x4_t*)(W + (size_t)(o0 + r) * DD + k0 + ac);
            bf16x4_t hi4, lo4;
#pragma unroll
            for (int e = 0; e < 4; ++e) {
                float x = v[e];
                __bf16 hh = (__bf16)x;
                hi4[e] = hh;
                lo4[e] = (__bf16)(x - (float)hh);
            }
            const int off = r * 128 + (((ac >> 3) ^ (r & 7)) << 4) + (ac & 7) * 2;
            *(bf16x4_t*)((char*)Bh + off) = hi4;
            *(bf16x4_t*)((char*)Bl + off) = lo4;
        }
        __syncthreads();
#pragma unroll
        for (int s = 0; s < 2; ++s) {
            bf16x8_t ah[2], al[2], bh[4], bl[4];
#pragma unroll
            for (int i = 0; i < 2; ++i) {
                const int row = wr * 32 + i * 16 + rl;
                const int byo = row * 128 + (((s * 4 + kq) ^ (row & 7)) << 4);
                ah[i] = *(const bf16x8_t*)((const char*)Ah + byo);
                al[i] = *(const bf16x8_t*)((const char*)Al + byo);
            }
#pragma unroll
            for (int j = 0; j < 4; ++j) {
                const int o = wc * 64 + j * 16 + rl;
                const int byo = o * 128 + (((s * 4 + kq) ^ (o & 7)) << 4);
                bh[j] = *(const bf16x8_t*)((const char*)Bh + byo);
                bl[j] = *(const bf16x8_t*)((const char*)Bl + byo);
            }
#pragma unroll
            for (int i = 0; i < 2; ++i)
#pragma unroll
                for (int j = 0; j < 4; ++j) {
                    acc[i][j] = __builtin_amdgcn_mfma_f32_16x16x32_bf16(ah[i], bh[j], acc[i][j], 0, 0, 0);
                    acc[i][j] = __builtin_amdgcn_mfma_f32_16x16x32_bf16(al[i], bh[j], acc[i][j], 0, 0, 0);
                    acc[i][j] = __builtin_amdgcn_mfma_f32_16x16x32_bf16(ah[i], bl[j], acc[i][j], 0, 0, 0);
                }
        }
        __syncthreads();
    }

#pragma unroll
    for (int i = 0; i < 2; ++i)
#pragma unroll
        for (int j = 0; j < 4; ++j) {
            const int row0 = n0 + wr * 32 + i * 16 + kq * 4;
            const int col  = o0 + wc * 64 + j * 16 + rl;
            _Float16* tp = t_h + ((size_t)b * NN + row0) * DD + col;
#pragma unroll
            for (int r2 = 0; r2 < 4; ++r2) tp[r2 * DD] = (_Float16)acc[i][j][r2];
            *(unsigned int*)(c0q + ((size_t)b * DD + col) * NN + swz(row0, col & 7)) =
                pk_fp8x4(16.f * acc[i][j][0], 16.f * acc[i][j][1],
                         16.f * acc[i][j][2], 16.f * acc[i][j][3]);
        }
}

// ================= diffusion step (fp8, NBUF=6, stage-ahead-3, counted vmcnt) =================
__device__ __forceinline__ void stage_tile_q(const unsigned char* __restrict__ aRow,
                                             const unsigned char* __restrict__ cRow,
                                             unsigned char* As, unsigned char* Bs,
                                             int wv, int sr, int sb, int k0) {
    gl2lds16(aRow + (size_t)(wv * 16 + sr) * NN + k0 + sb, As + wv * 1024);
#pragma unroll
    for (int q = 0; q < 2; ++q)
        gl2lds16(cRow + (size_t)((wv * 2 + q) * 16 + sr) * NN + k0 + sb,
                 Bs + (wv * 2 + q) * 1024);
}

template <bool LAST>
__global__ __launch_bounds__(256) void k_diffuse(const unsigned char* __restrict__ adjq,
                                                 const unsigned char* __restrict__ cinq,
                                                 unsigned char* __restrict__ coutq,
                                                 const unsigned char* __restrict__ c1q,
                                                 const unsigned char* __restrict__ c2q,
                                                 const _Float16* __restrict__ t_h,
                                                 float* __restrict__ out,
                                                 const float* __restrict__ convw,
                                                 const float* __restrict__ convb) {
    __shared__ __align__(16) unsigned char As[6][64 * 64];    // 6 x 4 KB
    __shared__ __align__(16) unsigned char Bs[6][128 * 64];   // 6 x 8 KB  (72 KB)

    const int tid = threadIdx.x;
    int n0, o0, b;
    pair_remap(n0, o0, b);
    const int lane = tid & 63, wv = tid >> 6;
    const int wr = wv >> 1, wc = wv & 1;
    const int rl = lane & 15, kq = lane >> 4;
    const int sr = lane >> 2, sb = (lane & 3) * 16;

    const unsigned char* aRow = adjq + (size_t)b * NN * NN + (size_t)n0 * NN;
    const unsigned char* cRow = cinq + (size_t)b * DD * NN + (size_t)o0 * NN;

    f32x4_t acc[2][4];
#pragma unroll
    for (int i = 0; i < 2; ++i)
#pragma unroll
        for (int j = 0; j < 4; ++j) acc[i][j] = (f32x4_t){0.f, 0.f, 0.f, 0.f};

    // prologue: stage tiles 0,1,2 into bufs 0,1,2
    stage_tile_q(aRow, cRow, As[0], Bs[0], wv, sr, sb, 0);
    stage_tile_q(aRow, cRow, As[1], Bs[1], wv, sr, sb, 64);
    stage_tile_q(aRow, cRow, As[2], Bs[2], wv, sr, sb, 128);

    int bcur = 0, bnxt = 3;   // incremental %6 buffer indices
    for (int t = 0; t < 32; ++t) {
        // stage tile (t+3)%32 into buf (t+3)%6 (tail wraps: redundant re-stage of
        // already-processed tiles keeps the vmcnt immediate constant)
        stage_tile_q(aRow, cRow, As[bnxt], Bs[bnxt], wv, sr, sb, ((t + 3) & 31) * 64);
        asm volatile("s_waitcnt vmcnt(9)" ::: "memory");   // tile t's 3 loads landed
        __builtin_amdgcn_s_barrier();                      // all waves' tile-t loads landed
        __builtin_amdgcn_sched_barrier(0);                 // keep ds_reads below (rule 18)
        const unsigned char* Ac = As[bcur];
        const unsigned char* Bc = Bs[bcur];
#pragma unroll
        for (int s = 0; s < 2; ++s) {
            long a[2], bb[4];
#pragma unroll
            for (int i = 0; i < 2; ++i) {
                const int row = wr * 32 + i * 16 + rl;
                a[i] = *(const long*)(Ac + row * 64 + (((s * 4 + kq) ^ (row & 7)) << 3));
            }
#pragma unroll
            for (int j = 0; j < 4; ++j) {
                const int o = wc * 64 + j * 16 + rl;
                bb[j] = *(const long*)(Bc + o * 64 + (((s * 4 + kq) ^ (o & 7)) << 3));
            }
#pragma unroll
            for (int i = 0; i < 2; ++i)
#pragma unroll
                for (int j = 0; j < 4; ++j)
                    acc[i][j] = __builtin_amdgcn_mfma_f32_16x16x32_fp8_fp8(a[i], bb[j], acc[i][j], 0, 0, 0);
        }
        bcur = (bcur == 5) ? 0 : bcur + 1;
        bnxt = (bnxt == 5) ? 0 : bnxt + 1;
        // ledger (NBUF=6, ahead=3): buf written at t was last read at compute(t-3);
        // any wave staging at t has passed barrier(t-1) => all finished compute(t-2).
    }

    // ---- epilogue ----
#pragma unroll
    for (int i = 0; i < 2; ++i)
#pragma unroll
        for (int j = 0; j < 4; ++j) {
            const int row0 = n0 + wr * 32 + i * 16 + kq * 4;
            const int col  = o0 + wc * 64 + j * 16 + rl;
            if (LAST) {
                const float cw0 = convw[0], cw1 = convw[1], cw2 = convw[2], cw3 = convw[3];
                const float cb  = convb[0];
                const float ru = 1.0f / 16.0f, rf = 1.0f / 4096.0f;
                float* op = out + ((size_t)b * NN + row0) * DD + col;
                const _Float16* tp = t_h + ((size_t)b * NN + row0) * DD + col;
                const int sa = swz(row0, col & 7);
                f32x4_t u1 = cvt_f32_fp8x4(*(const unsigned int*)(c1q + ((size_t)b * DD + col) * NN + sa));
                f32x4_t u2 = cvt_f32_fp8x4(*(const unsigned int*)(c2q + ((size_t)b * DD + col) * NN + sa));
#pragma unroll
                for (int r2 = 0; r2 < 4; ++r2) {
                    float v = cw0 * (float)tp[r2 * DD] + cw1 * ru * u1[r2] + cw2 * ru * u2[r2]
                            + cw3 * rf * acc[i][j][r2] + cb;
                    op[r2 * DD] = v >= 0.0f ? v : SLOPE * v;
                }
            } else {
                const float rs = 1.0f / 256.0f;   // acc -> 16*c_next
                *(unsigned int*)(coutq + ((size_t)b * DD + col) * NN + swz(row0, col & 7)) =
                    pk_fp8x4(rs * acc[i][j][0], rs * acc[i][j][1],
                             rs * acc[i][j][2], rs * acc[i][j][3]);
            }
        }
}

extern "C" void kernel_launch(void* const* d_in, const int* in_sizes, int n_in,
                              void* d_out, int out_size, void* d_ws, size_t ws_size,
                              hipStream_t stream) {
    const float* h   = (const float*)d_in[0];
    const float* adj = (const float*)d_in[1];
    const float* W   = (const float*)d_in[2];
    const float* cw  = (const float*)d_in[3];
    const float* cb  = (const float*)d_in[4];
    float* out = (float*)d_out;

    char* ws = (char*)d_ws;
    unsigned char* adjq = (unsigned char*)ws;                         // 32 MB
    unsigned char* c0q  = (unsigned char*)(ws + 33554432);            // 4 MB
    unsigned char* c1q  = (unsigned char*)(ws + 37748736);            // 4 MB
    unsigned char* c2q  = (unsigned char*)(ws + 41943040);            // 4 MB
    _Float16*      t_h  = (_Float16*)(ws + 46137344);                 // 8.4 MB (~52.5 MB)

    k_normadj<<<BATCH * NN / 4, 256, 0, stream>>>(adj, adjq);
    k_htrans<<<dim3(32, 2, BATCH), 256, 0, stream>>>(h, W, t_h, c0q);
    k_diffuse<false><<<dim3(32, 2, BATCH), 256, 0, stream>>>(adjq, c0q, c1q, nullptr, nullptr, nullptr, out, cw, cb);
    k_diffuse<false><<<dim3(32, 2, BATCH), 256, 0, stream>>>(adjq, c1q, c2q, nullptr, nullptr, nullptr, out, cw, cb);
    k_diffuse<true ><<<dim3(32, 2, BATCH), 256, 0, stream>>>(adjq, c2q, nullptr, c1q, c2q, t_h, out, cw, cb);
}